// Round 8
// baseline (767.363 us; speedup 1.0000x reference)
//
#include <hip/hip_runtime.h>
#include <stdint.h>

#define HH    256
#define DD    96
#define NH    6
#define WSZ   8

typedef __bf16 bf16_t;
typedef bf16_t bf16x8 __attribute__((ext_vector_type(8)));
typedef short  s16x4  __attribute__((ext_vector_type(4)));
typedef float  f32x4  __attribute__((ext_vector_type(4)));

union U2  { bf16_t h[2]; uint32_t u; };
union Upk { uint32_t u[2]; s16x4 s; };

static __device__ __forceinline__ uint32_t pack2(float a, float b) {
    U2 x; x.h[0] = (bf16_t)a; x.h[1] = (bf16_t)b; return x.u;
}

static __device__ __forceinline__ f32x4 mfma16(s16x4 a, s16x4 b, f32x4 c) {
#if __has_builtin(__builtin_amdgcn_mfma_f32_16x16x16bf16_1k)
    return __builtin_amdgcn_mfma_f32_16x16x16bf16_1k(a, b, c, 0, 0, 0);
#else
    f32x4 d;
    asm volatile("v_mfma_f32_16x16x16_bf16 %0, %1, %2, %3"
                 : "=v"(d) : "v"(a), "v"(b), "v"(c));
    return d;
#endif
}

// ---- workspace layout (bytes) ----
#define OFF_WQT_HI 0        // Q,K transposed A-frags: 36 frags * 512 el = 36864 B
#define OFF_WQT_LO 36864
#define OFF_WV_HI  73728    // V B-frags: 18 frags * 512 el = 18432 B
#define OFF_WV_LO  92160
#define OFF_WO_HI  110592   // out-proj B-frags: 18 frags
#define OFF_WO_LO  129024
#define OFF_RPE    147456   // 6*64*64 f32 = 98304 B, layout [h][q][k]
// total 245760 B

// ---- LDS overlay arena: 32768 B ----
// phase 0/1: xs_hi [64][128]swz @0 (16384) | xs_lo @16384 (16384)
// phase 2/3: o_hi  [64][128]swz @0         | o_lo  @16384
#define LDS_BYTES 32768

// swizzled element index into a [64][128] bf16 buffer (16B-chunk XOR)
static __device__ __forceinline__ int swz(int row, int col) {
    return row * 128 + ((((col >> 3) ^ (row & 15)) & 15) << 3) + (col & 7);
}

__global__ __launch_bounds__(256)
void prep_kernel(const float* __restrict__ wqkv, const float* __restrict__ wout,
                 const float* __restrict__ rpe, char* __restrict__ ws)
{
    bf16_t* wqt_hi = (bf16_t*)(ws + OFF_WQT_HI);
    bf16_t* wqt_lo = (bf16_t*)(ws + OFF_WQT_LO);
    bf16_t* wv_hi  = (bf16_t*)(ws + OFF_WV_HI);
    bf16_t* wv_lo  = (bf16_t*)(ws + OFF_WV_LO);
    bf16_t* wo_hi  = (bf16_t*)(ws + OFF_WO_HI);
    bf16_t* wo_lo  = (bf16_t*)(ws + OFF_WO_LO);
    float*  rpe_b  = (float*)(ws + OFF_RPE);

    int idx = blockIdx.x * 256 + threadIdx.x;
    int j = idx & 7, lane = (idx >> 3) & 63, frag = idx >> 9;
    int c = lane & 15, g = lane >> 4;

    // Q,K transposed A-frags: lane(c,g) holds W^T[head-dim c][k=ks*32+g*8+j]
    if (idx < 18432) {
        int ks = frag % 3, r2 = frag / 3, wh = r2 % 6, t = r2 / 6;  // t: 0=Q,1=K
        int k = ks * 32 + g * 8 + j;
        float v = wqkv[k * 288 + t * 96 + wh * 16 + c];
        bf16_t h = (bf16_t)v;
        wqt_hi[idx] = h;
        wqt_lo[idx] = (bf16_t)(v - (float)h);
    }
    // V B-frags: lane(c,g) holds Wv[k=ks*32+g*8+j][n=wh*16+c]
    if (idx < 9216) {
        int ks = frag % 3, wh = frag / 3;
        int k = ks * 32 + g * 8 + j;
        float v = wqkv[k * 288 + 192 + wh * 16 + c];
        bf16_t h = (bf16_t)v;
        wv_hi[idx] = h;
        wv_lo[idx] = (bf16_t)(v - (float)h);
        // out-proj B-frags (same shape)
        float v2 = wout[k * 96 + wh * 16 + c];
        bf16_t h2 = (bf16_t)v2;
        wo_hi[idx] = h2;
        wo_lo[idx] = (bf16_t)(v2 - (float)h2);
    }
    // expanded rpe bias: [h][q][k]
    if (idx < 24576) {
        int h = idx >> 12, r = idx & 4095, q = r >> 6, k = r & 63;
        int qr = q >> 3, qc = q & 7, kr = k >> 3, kc = k & 7;
        rpe_b[idx] = rpe[((qr - kr + 7) * 15 + (qc - kc + 7)) * NH + h];
    }
}

__global__ __launch_bounds__(384, 4)
void swin_mfma(const float* __restrict__ x,
               const float* __restrict__ b_qkv,
               const float* __restrict__ b_out,
               const char*  __restrict__ ws,
               float* __restrict__ out)
{
    extern __shared__ char smem[];
    bf16_t* xs_hi = (bf16_t*)(smem);            // phase 0/1 (swizzled [64][128])
    bf16_t* xs_lo = (bf16_t*)(smem + 16384);
    bf16_t* o_hi  = (bf16_t*)(smem);            // phase 2/3 overlay
    bf16_t* o_lo  = (bf16_t*)(smem + 16384);

    const bf16_t* wqt_hi = (const bf16_t*)(ws + OFF_WQT_HI);
    const bf16_t* wqt_lo = (const bf16_t*)(ws + OFF_WQT_LO);
    const bf16_t* wv_hi  = (const bf16_t*)(ws + OFF_WV_HI);
    const bf16_t* wv_lo  = (const bf16_t*)(ws + OFF_WV_LO);
    const bf16_t* wo_hi  = (const bf16_t*)(ws + OFF_WO_HI);
    const bf16_t* wo_lo  = (const bf16_t*)(ws + OFF_WO_LO);
    const float*  rpe_b  = (const float*)(ws + OFF_RPE);

    const int blk = blockIdx.x;
    const int b   = blk >> 8;          // 256 block-slots per batch image
    const int wi  = (blk >> 3) & 31;
    const int wj0 = (blk & 7) * 4;     // 4 consecutive windows per block

    const int tid  = threadIdx.x;
    const int lane = tid & 63;
    const int w    = tid >> 6;      // wave = head
    const int g    = lane >> 4;     // lane group 0..3
    const int c    = lane & 15;

    const f32x4 zf = {0.f, 0.f, 0.f, 0.f};
    const int e_wi = (wi == 31);

    for (int ww = 0; ww < 4; ++ww) {
        const int wj = wj0 + ww;

        __syncthreads();   // previous iteration's o-reads done -> xs overlay legal

        // ---- Phase 0: stage x -> swizzled xs_hi/xs_lo (shifted gather) ----
        #pragma unroll
        for (int it = 0; it < 4; ++it) {
            int f4  = tid + it * 384;          // float4 index over [64][24]
            int row = f4 / 24, c4 = f4 - row * 24;
            int r = row >> 3, cl = row & 7;
            int gh = (wi * WSZ + r + 4) & 255;
            int gw = (wj * WSZ + cl + 4) & 255;
            const float4 v = *(const float4*)(x + (((size_t)b * HH + gh) * HH + gw) * DD + c4 * 4);
            float f0 = v.x, f1 = v.y, f2 = v.z, f3 = v.w;
            bf16_t h0 = (bf16_t)f0, h1 = (bf16_t)f1, h2 = (bf16_t)f2, h3 = (bf16_t)f3;
            uint2 hv, lv;
            hv.x = pack2(f0, f1); hv.y = pack2(f2, f3);
            lv.x = pack2(f0 - (float)h0, f1 - (float)h1);
            lv.y = pack2(f2 - (float)h2, f3 - (float)h3);
            int e = swz(row, c4 * 4);
            *(uint2*)&xs_hi[e] = hv;
            *(uint2*)&xs_lo[e] = lv;
        }
        __syncthreads();

        // ---- Phase 1: QKV projection (split-bf16, 3-term) ----
        f32x4 aq[4], akk[4], av[4];
        {
            const float4 bq4 = *(const float4*)&b_qkv[w * 16 + 4 * g];
            const float4 bk4 = *(const float4*)&b_qkv[96 + w * 16 + 4 * g];
            const float  bv  = b_qkv[192 + w * 16 + c];
            #pragma unroll
            for (int t4 = 0; t4 < 4; ++t4) {
                aq[t4]  = (f32x4){bq4.x, bq4.y, bq4.z, bq4.w};
                akk[t4] = (f32x4){bk4.x, bk4.y, bk4.z, bk4.w};
                av[t4]  = (f32x4){bv, bv, bv, bv};
            }
        }
        #pragma unroll
        for (int ks = 0; ks < 3; ++ks) {
            bf16x8 ah[4], al[4];
            #pragma unroll
            for (int mt = 0; mt < 4; ++mt) {
                int e = (mt * 16 + c) * 128 + (((ks * 4 + g) ^ c) << 3);
                ah[mt] = *(const bf16x8*)&xs_hi[e];
                al[mt] = *(const bf16x8*)&xs_lo[e];
            }
            const bf16x8 qh = *(const bf16x8*)&wqt_hi[(w * 3 + ks) * 512 + lane * 8];
            const bf16x8 ql = *(const bf16x8*)&wqt_lo[(w * 3 + ks) * 512 + lane * 8];
            const bf16x8 kh = *(const bf16x8*)&wqt_hi[((6 + w) * 3 + ks) * 512 + lane * 8];
            const bf16x8 kl = *(const bf16x8*)&wqt_lo[((6 + w) * 3 + ks) * 512 + lane * 8];
            const bf16x8 vh = *(const bf16x8*)&wv_hi[(w * 3 + ks) * 512 + lane * 8];
            const bf16x8 vl = *(const bf16x8*)&wv_lo[(w * 3 + ks) * 512 + lane * 8];
            #pragma unroll
            for (int mt = 0; mt < 4; ++mt) {
                aq[mt] = __builtin_amdgcn_mfma_f32_16x16x32_bf16(qh, ah[mt], aq[mt], 0, 0, 0);
                aq[mt] = __builtin_amdgcn_mfma_f32_16x16x32_bf16(ql, ah[mt], aq[mt], 0, 0, 0);
                aq[mt] = __builtin_amdgcn_mfma_f32_16x16x32_bf16(qh, al[mt], aq[mt], 0, 0, 0);
                akk[mt] = __builtin_amdgcn_mfma_f32_16x16x32_bf16(kh, ah[mt], akk[mt], 0, 0, 0);
                akk[mt] = __builtin_amdgcn_mfma_f32_16x16x32_bf16(kl, ah[mt], akk[mt], 0, 0, 0);
                akk[mt] = __builtin_amdgcn_mfma_f32_16x16x32_bf16(kh, al[mt], akk[mt], 0, 0, 0);
                av[mt] = __builtin_amdgcn_mfma_f32_16x16x32_bf16(ah[mt], vh, av[mt], 0, 0, 0);
                av[mt] = __builtin_amdgcn_mfma_f32_16x16x32_bf16(ah[mt], vl, av[mt], 0, 0, 0);
                av[mt] = __builtin_amdgcn_mfma_f32_16x16x32_bf16(al[mt], vh, av[mt], 0, 0, 0);
            }
        }
        __syncthreads();   // all proj reads of xs done -> o overlay becomes legal

        // convert proj outputs to 16x16x16 MFMA fragments (all lane-local)
        s16x4 aqb[4], akb[4], avb[4];
        #pragma unroll
        for (int t = 0; t < 4; ++t) {
            Upk uq, uk, uv;
            uq.u[0] = pack2(aq[t][0] * 0.25f, aq[t][1] * 0.25f);   // fold 1/sqrt(dk)
            uq.u[1] = pack2(aq[t][2] * 0.25f, aq[t][3] * 0.25f);
            uk.u[0] = pack2(akk[t][0], akk[t][1]);
            uk.u[1] = pack2(akk[t][2], akk[t][3]);
            uv.u[0] = pack2(av[t][0], av[t][1]);
            uv.u[1] = pack2(av[t][2], av[t][3]);
            aqb[t] = uq.s; akb[t] = uk.s; avb[t] = uv.s;
        }

        // ---- Phase 2: attention, fully in registers ----
        const float* rpe_w = rpe_b + w * 4096;
        const int e_wj = (wj == 31);
        const bool edge = e_wi || e_wj;
        int rk[4][4];
        #pragma unroll
        for (int kt = 0; kt < 4; ++kt)
            #pragma unroll
            for (int i = 0; i < 4; ++i) {
                int k = kt * 16 + g * 4 + i;
                int kr = k >> 3, kc = k & 7;
                rk[kt][i] = (e_wi ? (kr >= 4 ? 2 : 1) : 0) * 3 + (e_wj ? (kc >= 4 ? 2 : 1) : 0);
            }

        #pragma unroll
        for (int nt = 0; nt < 4; ++nt) {
            f32x4 stc[4];
            #pragma unroll
            for (int kt = 0; kt < 4; ++kt)
                stc[kt] = mfma16(akb[kt], aqb[nt], zf);

            int q = nt * 16 + c, qr = q >> 3, qc = q & 7;
            int rq = (e_wi ? (qr >= 4 ? 2 : 1) : 0) * 3 + (e_wj ? (qc >= 4 ? 2 : 1) : 0);
            float sv[16];
            float m = -3.0e38f;
            #pragma unroll
            for (int kt = 0; kt < 4; ++kt) {
                const float4 rv = *(const float4*)&rpe_w[q * 64 + kt * 16 + g * 4];
                #pragma unroll
                for (int i = 0; i < 4; ++i) {
                    float s = stc[kt][i] + ((const float*)&rv)[i];
                    if (edge && (rk[kt][i] != rq)) s = -1e9f;
                    sv[kt * 4 + i] = s;
                    m = fmaxf(m, s);
                }
            }
            m = fmaxf(m, __shfl_xor(m, 16));
            m = fmaxf(m, __shfl_xor(m, 32));
            float sum = 0.f;
            #pragma unroll
            for (int e = 0; e < 16; ++e) { sv[e] = __expf(sv[e] - m); sum += sv[e]; }
            sum += __shfl_xor(sum, 16);
            sum += __shfl_xor(sum, 32);
            float rinv = 1.0f / sum;

            f32x4 oa = zf;
            #pragma unroll
            for (int ks2 = 0; ks2 < 4; ++ks2) {
                Upk pb;
                pb.u[0] = pack2(sv[ks2 * 4 + 0] * rinv, sv[ks2 * 4 + 1] * rinv);
                pb.u[1] = pack2(sv[ks2 * 4 + 2] * rinv, sv[ks2 * 4 + 3] * rinv);
                oa = mfma16(avb[ks2], pb.s, oa);
            }
            // write O (split) into swizzled o buffers: row=q, cols w*16+4g..+3
            {
                int row = nt * 16 + c;
                int colb = w * 16 + 4 * g;
                float f0 = oa[0], f1 = oa[1], f2 = oa[2], f3 = oa[3];
                bf16_t h0 = (bf16_t)f0, h1 = (bf16_t)f1, h2 = (bf16_t)f2, h3 = (bf16_t)f3;
                uint2 hv, lv;
                hv.x = pack2(f0, f1); hv.y = pack2(f2, f3);
                lv.x = pack2(f0 - (float)h0, f1 - (float)h1);
                lv.y = pack2(f2 - (float)h2, f3 - (float)h3);
                int e = swz(row, colb);
                *(uint2*)&o_hi[e] = hv;
                *(uint2*)&o_lo[e] = lv;
            }
        }
        __syncthreads();

        // ---- Phase 3: out-projection (split-bf16, 3-term). C[row=mt*16+4g+i][col=w*16+c] ----
        f32x4 acc3[4];
        {
            const float boc = b_out[w * 16 + c];
            #pragma unroll
            for (int mt = 0; mt < 4; ++mt) acc3[mt] = (f32x4){boc, boc, boc, boc};
        }
        #pragma unroll
        for (int ks = 0; ks < 3; ++ks) {
            bf16x8 ah[4], al[4];
            #pragma unroll
            for (int mt = 0; mt < 4; ++mt) {
                int e = (mt * 16 + c) * 128 + (((ks * 4 + g) ^ c) << 3);
                ah[mt] = *(const bf16x8*)&o_hi[e];
                al[mt] = *(const bf16x8*)&o_lo[e];
            }
            const bf16x8 bh = *(const bf16x8*)&wo_hi[(w * 3 + ks) * 512 + lane * 8];
            const bf16x8 bl = *(const bf16x8*)&wo_lo[(w * 3 + ks) * 512 + lane * 8];
            #pragma unroll
            for (int mt = 0; mt < 4; ++mt) {
                acc3[mt] = __builtin_amdgcn_mfma_f32_16x16x32_bf16(ah[mt], bh, acc3[mt], 0, 0, 0);
                acc3[mt] = __builtin_amdgcn_mfma_f32_16x16x32_bf16(ah[mt], bl, acc3[mt], 0, 0, 0);
                acc3[mt] = __builtin_amdgcn_mfma_f32_16x16x32_bf16(al[mt], bh, acc3[mt], 0, 0, 0);
            }
        }
        // store (shifted scatter): lane(c,g) holds out[row=mt*16+g*4+i][col=w*16+c]
        #pragma unroll
        for (int mt = 0; mt < 4; ++mt)
            #pragma unroll
            for (int i = 0; i < 4; ++i) {
                int row = mt * 16 + g * 4 + i;
                int r = row >> 3, cl = row & 7;
                int gh = (wi * WSZ + r + 4) & 255;
                int gw = (wj * WSZ + cl + 4) & 255;
                out[(((size_t)b * HH + gh) * HH + gw) * DD + w * 16 + c] = acc3[mt][i];
            }
    }
}

extern "C" void kernel_launch(void* const* d_in, const int* in_sizes, int n_in,
                              void* d_out, int out_size, void* d_ws, size_t ws_size,
                              hipStream_t stream) {
    const float* x    = (const float*)d_in[0];
    const float* wqkv = (const float*)d_in[1];
    const float* bqkv = (const float*)d_in[2];
    const float* wout = (const float*)d_in[3];
    const float* bout = (const float*)d_in[4];
    const float* rpe  = (const float*)d_in[5];
    float* out = (float*)d_out;
    char* ws = (char*)d_ws;

    const int B = in_sizes[0] / (HH * HH * DD);

    hipLaunchKernelGGL(prep_kernel, dim3(96), dim3(256), 0, stream, wqkv, wout, rpe, ws);
    hipLaunchKernelGGL(swin_mfma, dim3(B * 256), dim3(384), LDS_BYTES, stream,
                       x, bqkv, bout, (const char*)ws, out);
}

// Round 9
// 252.453 us; speedup vs baseline: 3.0396x; 3.0396x over previous
//
#include <hip/hip_runtime.h>
#include <stdint.h>

#define HH    256
#define DD    96
#define NH    6
#define WSZ   8

typedef __bf16 bf16_t;
typedef bf16_t bf16x8 __attribute__((ext_vector_type(8)));
typedef short  s16x4  __attribute__((ext_vector_type(4)));
typedef float  f32x4  __attribute__((ext_vector_type(4)));

union U2  { bf16_t h[2]; uint32_t u; };
union Upk { uint32_t u[2]; s16x4 s; };

static __device__ __forceinline__ uint32_t pack2(float a, float b) {
    U2 x; x.h[0] = (bf16_t)a; x.h[1] = (bf16_t)b; return x.u;
}

static __device__ __forceinline__ f32x4 mfma16(s16x4 a, s16x4 b, f32x4 c) {
#if __has_builtin(__builtin_amdgcn_mfma_f32_16x16x16bf16_1k)
    return __builtin_amdgcn_mfma_f32_16x16x16bf16_1k(a, b, c, 0, 0, 0);
#else
    f32x4 d;
    asm volatile("v_mfma_f32_16x16x16_bf16 %0, %1, %2, %3"
                 : "=v"(d) : "v"(a), "v"(b), "v"(c));
    return d;
#endif
}

// ---- workspace layout (bytes) ----
#define OFF_WQT_HI 0        // Q,K transposed A-frags: 36 frags * 512 el = 36864 B
#define OFF_WQT_LO 36864
#define OFF_WV_HI  73728    // V B-frags: 18 frags * 512 el = 18432 B
#define OFF_WV_LO  92160
#define OFF_WO_HI  110592   // out-proj B-frags: 18 frags
#define OFF_WO_LO  129024
#define OFF_RPE    147456   // 6*64*64 f32 = 98304 B, layout [h][q][k]
// total 245760 B

// ---- LDS overlay arena: 16384 B ----
// phase 0/1: xs_hi [64][128]swz (16384)
// phase 2/3: o_hi  [64][128]swz (overlay)
#define LDS_BYTES 16384

// swizzled element index into a [64][128] bf16 buffer (16B-chunk XOR)
static __device__ __forceinline__ int swz(int row, int col) {
    return row * 128 + ((((col >> 3) ^ (row & 15)) & 15) << 3) + (col & 7);
}

__global__ __launch_bounds__(256)
void prep_kernel(const float* __restrict__ wqkv, const float* __restrict__ wout,
                 const float* __restrict__ rpe, char* __restrict__ ws)
{
    bf16_t* wqt_hi = (bf16_t*)(ws + OFF_WQT_HI);
    bf16_t* wqt_lo = (bf16_t*)(ws + OFF_WQT_LO);
    bf16_t* wv_hi  = (bf16_t*)(ws + OFF_WV_HI);
    bf16_t* wv_lo  = (bf16_t*)(ws + OFF_WV_LO);
    bf16_t* wo_hi  = (bf16_t*)(ws + OFF_WO_HI);
    bf16_t* wo_lo  = (bf16_t*)(ws + OFF_WO_LO);
    float*  rpe_b  = (float*)(ws + OFF_RPE);

    int idx = blockIdx.x * 256 + threadIdx.x;
    int j = idx & 7, lane = (idx >> 3) & 63, frag = idx >> 9;
    int c = lane & 15, g = lane >> 4;

    // Q,K transposed A-frags: lane(c,g) holds W^T[head-dim c][k=ks*32+g*8+j]
    if (idx < 18432) {
        int ks = frag % 3, r2 = frag / 3, wh = r2 % 6, t = r2 / 6;  // t: 0=Q,1=K
        int k = ks * 32 + g * 8 + j;
        float v = wqkv[k * 288 + t * 96 + wh * 16 + c];
        bf16_t h = (bf16_t)v;
        wqt_hi[idx] = h;
        wqt_lo[idx] = (bf16_t)(v - (float)h);
    }
    // V B-frags: lane(c,g) holds Wv[k=ks*32+g*8+j][n=wh*16+c]
    if (idx < 9216) {
        int ks = frag % 3, wh = frag / 3;
        int k = ks * 32 + g * 8 + j;
        float v = wqkv[k * 288 + 192 + wh * 16 + c];
        bf16_t h = (bf16_t)v;
        wv_hi[idx] = h;
        wv_lo[idx] = (bf16_t)(v - (float)h);
        // out-proj B-frags (same shape)
        float v2 = wout[k * 96 + wh * 16 + c];
        bf16_t h2 = (bf16_t)v2;
        wo_hi[idx] = h2;
        wo_lo[idx] = (bf16_t)(v2 - (float)h2);
    }
    // expanded rpe bias: [h][q][k]
    if (idx < 24576) {
        int h = idx >> 12, r = idx & 4095, q = r >> 6, k = r & 63;
        int qr = q >> 3, qc = q & 7, kr = k >> 3, kc = k & 7;
        rpe_b[idx] = rpe[((qr - kr + 7) * 15 + (qc - kc + 7)) * NH + h];
    }
}

__global__ __launch_bounds__(384, 4)
void swin_mfma(const float* __restrict__ x,
               const float* __restrict__ b_qkv,
               const float* __restrict__ b_out,
               const char*  __restrict__ ws,
               float* __restrict__ out)
{
    extern __shared__ char smem[];
    bf16_t* xs_hi = (bf16_t*)(smem);            // phase 0/1 (swizzled [64][128])
    bf16_t* o_hi  = (bf16_t*)(smem);            // phase 2/3 overlay

    const bf16_t* wqt_hi = (const bf16_t*)(ws + OFF_WQT_HI);
    const bf16_t* wqt_lo = (const bf16_t*)(ws + OFF_WQT_LO);
    const bf16_t* wv_hi  = (const bf16_t*)(ws + OFF_WV_HI);
    const bf16_t* wv_lo  = (const bf16_t*)(ws + OFF_WV_LO);
    const bf16_t* wo_hi  = (const bf16_t*)(ws + OFF_WO_HI);
    const bf16_t* wo_lo  = (const bf16_t*)(ws + OFF_WO_LO);
    const float*  rpe_b  = (const float*)(ws + OFF_RPE);

    const int blk = blockIdx.x;
    const int b   = blk >> 10;
    const int wi  = (blk >> 5) & 31;
    const int wj  = blk & 31;

    const int tid  = threadIdx.x;
    const int lane = tid & 63;
    const int w    = tid >> 6;      // wave = head
    const int g    = lane >> 4;     // lane group 0..3
    const int c    = lane & 15;

    const f32x4 zf = {0.f, 0.f, 0.f, 0.f};

    // ---- Phase 0: stage x (bf16-hi only) -> swizzled xs_hi (shifted gather) ----
    #pragma unroll
    for (int it = 0; it < 4; ++it) {
        int f4  = tid + it * 384;          // float4 index over [64][24]
        int row = f4 / 24, c4 = f4 - row * 24;
        int r = row >> 3, cl = row & 7;
        int gh = (wi * WSZ + r + 4) & 255;
        int gw = (wj * WSZ + cl + 4) & 255;
        const float4 v = *(const float4*)(x + (((size_t)b * HH + gh) * HH + gw) * DD + c4 * 4);
        uint2 hv;
        hv.x = pack2(v.x, v.y); hv.y = pack2(v.z, v.w);
        *(uint2*)&xs_hi[swz(row, c4 * 4)] = hv;
    }
    __syncthreads();

    // ---- Phase 1: QKV projection (2-term split: hi*Whi + hi*Wlo) ----
    // Q,K transposed: lane(c,g) holds {Q,K}^T[dk=4g+i][pos=pt*16+c]
    // V normal:       lane(c,g) holds V[pos=pt*16+4g+i][dk=c]
    f32x4 aq[4], akk[4], av[4];
    {
        const float4 bq4 = *(const float4*)&b_qkv[w * 16 + 4 * g];
        const float4 bk4 = *(const float4*)&b_qkv[96 + w * 16 + 4 * g];
        const float  bv  = b_qkv[192 + w * 16 + c];
        #pragma unroll
        for (int t4 = 0; t4 < 4; ++t4) {
            aq[t4]  = (f32x4){bq4.x, bq4.y, bq4.z, bq4.w};
            akk[t4] = (f32x4){bk4.x, bk4.y, bk4.z, bk4.w};
            av[t4]  = (f32x4){bv, bv, bv, bv};
        }
    }
    #pragma unroll
    for (int ks = 0; ks < 3; ++ks) {
        bf16x8 ah[4];
        #pragma unroll
        for (int mt = 0; mt < 4; ++mt) {
            int e = (mt * 16 + c) * 128 + (((ks * 4 + g) ^ c) << 3);
            ah[mt] = *(const bf16x8*)&xs_hi[e];
        }
        const bf16x8 qh = *(const bf16x8*)&wqt_hi[(w * 3 + ks) * 512 + lane * 8];
        const bf16x8 ql = *(const bf16x8*)&wqt_lo[(w * 3 + ks) * 512 + lane * 8];
        const bf16x8 kh = *(const bf16x8*)&wqt_hi[((6 + w) * 3 + ks) * 512 + lane * 8];
        const bf16x8 kl = *(const bf16x8*)&wqt_lo[((6 + w) * 3 + ks) * 512 + lane * 8];
        const bf16x8 vh = *(const bf16x8*)&wv_hi[(w * 3 + ks) * 512 + lane * 8];
        const bf16x8 vl = *(const bf16x8*)&wv_lo[(w * 3 + ks) * 512 + lane * 8];
        #pragma unroll
        for (int mt = 0; mt < 4; ++mt) {
            aq[mt]  = __builtin_amdgcn_mfma_f32_16x16x32_bf16(qh, ah[mt], aq[mt], 0, 0, 0);
            aq[mt]  = __builtin_amdgcn_mfma_f32_16x16x32_bf16(ql, ah[mt], aq[mt], 0, 0, 0);
            akk[mt] = __builtin_amdgcn_mfma_f32_16x16x32_bf16(kh, ah[mt], akk[mt], 0, 0, 0);
            akk[mt] = __builtin_amdgcn_mfma_f32_16x16x32_bf16(kl, ah[mt], akk[mt], 0, 0, 0);
            av[mt]  = __builtin_amdgcn_mfma_f32_16x16x32_bf16(ah[mt], vh, av[mt], 0, 0, 0);
            av[mt]  = __builtin_amdgcn_mfma_f32_16x16x32_bf16(ah[mt], vl, av[mt], 0, 0, 0);
        }
    }
    __syncthreads();   // all proj reads of xs done -> o overlay becomes legal

    // convert proj outputs to 16x16x16 MFMA fragments (all lane-local)
    s16x4 aqb[4], akb[4], avb[4];
    #pragma unroll
    for (int t = 0; t < 4; ++t) {
        Upk uq, uk, uv;
        uq.u[0] = pack2(aq[t][0] * 0.25f, aq[t][1] * 0.25f);   // fold 1/sqrt(dk)
        uq.u[1] = pack2(aq[t][2] * 0.25f, aq[t][3] * 0.25f);
        uk.u[0] = pack2(akk[t][0], akk[t][1]);
        uk.u[1] = pack2(akk[t][2], akk[t][3]);
        uv.u[0] = pack2(av[t][0], av[t][1]);
        uv.u[1] = pack2(av[t][2], av[t][3]);
        aqb[t] = uq.s; akb[t] = uk.s; avb[t] = uv.s;
    }

    // ---- Phase 2: attention, fully in registers ----
    const float* rpe_w = rpe_b + w * 4096;
    const int e_wi = (wi == 31), e_wj = (wj == 31);
    const bool edge = e_wi || e_wj;
    int rk[4][4];
    #pragma unroll
    for (int kt = 0; kt < 4; ++kt)
        #pragma unroll
        for (int i = 0; i < 4; ++i) {
            int k = kt * 16 + g * 4 + i;
            int kr = k >> 3, kc = k & 7;
            rk[kt][i] = (e_wi ? (kr >= 4 ? 2 : 1) : 0) * 3 + (e_wj ? (kc >= 4 ? 2 : 1) : 0);
        }

    #pragma unroll
    for (int nt = 0; nt < 4; ++nt) {
        // S^T column tile: stc[kt] holds S^T[k=kt*16+4g+i][q=nt*16+c]
        f32x4 stc[4];
        #pragma unroll
        for (int kt = 0; kt < 4; ++kt)
            stc[kt] = mfma16(akb[kt], aqb[nt], zf);

        int q = nt * 16 + c, qr = q >> 3, qc = q & 7;
        int rq = (e_wi ? (qr >= 4 ? 2 : 1) : 0) * 3 + (e_wj ? (qc >= 4 ? 2 : 1) : 0);
        float sv[16];
        float m = -3.0e38f;
        #pragma unroll
        for (int kt = 0; kt < 4; ++kt) {
            const float4 rv = *(const float4*)&rpe_w[q * 64 + kt * 16 + g * 4];
            #pragma unroll
            for (int i = 0; i < 4; ++i) {
                float s = stc[kt][i] + ((const float*)&rv)[i];
                if (edge && (rk[kt][i] != rq)) s = -1e9f;
                sv[kt * 4 + i] = s;
                m = fmaxf(m, s);
            }
        }
        m = fmaxf(m, __shfl_xor(m, 16));
        m = fmaxf(m, __shfl_xor(m, 32));
        float sum = 0.f;
        #pragma unroll
        for (int e = 0; e < 16; ++e) { sv[e] = __expf(sv[e] - m); sum += sv[e]; }
        sum += __shfl_xor(sum, 16);
        sum += __shfl_xor(sum, 32);
        float rinv = 1.0f / sum;

        // PV: O^T tile = sum_ks V^T-frag x P^T-frag (both lane-local)
        f32x4 oa = zf;
        #pragma unroll
        for (int ks2 = 0; ks2 < 4; ++ks2) {
            Upk pb;
            pb.u[0] = pack2(sv[ks2 * 4 + 0] * rinv, sv[ks2 * 4 + 1] * rinv);
            pb.u[1] = pack2(sv[ks2 * 4 + 2] * rinv, sv[ks2 * 4 + 3] * rinv);
            oa = mfma16(avb[ks2], pb.s, oa);
        }
        // write O (bf16-hi only) into swizzled o buffer: row=q, cols w*16+4g..+3
        {
            uint2 hv;
            hv.x = pack2(oa[0], oa[1]);
            hv.y = pack2(oa[2], oa[3]);
            *(uint2*)&o_hi[swz(nt * 16 + c, w * 16 + 4 * g)] = hv;
        }
    }
    __syncthreads();

    // ---- Phase 3: out-projection (2-term split). C[row=mt*16+4g+i][col=w*16+c] ----
    f32x4 acc3[4];
    {
        const float boc = b_out[w * 16 + c];
        #pragma unroll
        for (int mt = 0; mt < 4; ++mt) acc3[mt] = (f32x4){boc, boc, boc, boc};
    }
    #pragma unroll
    for (int ks = 0; ks < 3; ++ks) {
        bf16x8 ah[4];
        #pragma unroll
        for (int mt = 0; mt < 4; ++mt) {
            int e = (mt * 16 + c) * 128 + (((ks * 4 + g) ^ c) << 3);
            ah[mt] = *(const bf16x8*)&o_hi[e];
        }
        const bf16x8 bh = *(const bf16x8*)&wo_hi[(w * 3 + ks) * 512 + lane * 8];
        const bf16x8 bl = *(const bf16x8*)&wo_lo[(w * 3 + ks) * 512 + lane * 8];
        #pragma unroll
        for (int mt = 0; mt < 4; ++mt) {
            acc3[mt] = __builtin_amdgcn_mfma_f32_16x16x32_bf16(ah[mt], bh, acc3[mt], 0, 0, 0);
            acc3[mt] = __builtin_amdgcn_mfma_f32_16x16x32_bf16(ah[mt], bl, acc3[mt], 0, 0, 0);
        }
    }
    // store (shifted scatter): lane(c,g) holds out[row=mt*16+g*4+i][col=w*16+c]
    #pragma unroll
    for (int mt = 0; mt < 4; ++mt)
        #pragma unroll
        for (int i = 0; i < 4; ++i) {
            int row = mt * 16 + g * 4 + i;
            int r = row >> 3, cl = row & 7;
            int gh = (wi * WSZ + r + 4) & 255;
            int gw = (wj * WSZ + cl + 4) & 255;
            out[(((size_t)b * HH + gh) * HH + gw) * DD + w * 16 + c] = acc3[mt][i];
        }
}

extern "C" void kernel_launch(void* const* d_in, const int* in_sizes, int n_in,
                              void* d_out, int out_size, void* d_ws, size_t ws_size,
                              hipStream_t stream) {
    const float* x    = (const float*)d_in[0];
    const float* wqkv = (const float*)d_in[1];
    const float* bqkv = (const float*)d_in[2];
    const float* wout = (const float*)d_in[3];
    const float* bout = (const float*)d_in[4];
    const float* rpe  = (const float*)d_in[5];
    float* out = (float*)d_out;
    char* ws = (char*)d_ws;

    const int B = in_sizes[0] / (HH * HH * DD);

    hipLaunchKernelGGL(prep_kernel, dim3(96), dim3(256), 0, stream, wqkv, wout, rpe, ws);
    hipLaunchKernelGGL(swin_mfma, dim3(B * 1024), dim3(384), LDS_BYTES, stream,
                       x, bqkv, bout, (const char*)ws, out);
}

// Round 10
// 215.192 us; speedup vs baseline: 3.5659x; 1.1732x over previous
//
#include <hip/hip_runtime.h>
#include <stdint.h>

#define HH    256
#define DD    96
#define NH    6
#define WSZ   8

typedef __bf16 bf16_t;
typedef bf16_t bf16x8 __attribute__((ext_vector_type(8)));
typedef short  s16x4  __attribute__((ext_vector_type(4)));
typedef float  f32x4  __attribute__((ext_vector_type(4)));

union U2  { bf16_t h[2]; uint32_t u; };
union Upk { uint32_t u[2]; s16x4 s; };

#define LOG2E 1.44269504088896f

static __device__ __forceinline__ uint32_t pack2(float a, float b) {
    U2 x; x.h[0] = (bf16_t)a; x.h[1] = (bf16_t)b; return x.u;
}

static __device__ __forceinline__ f32x4 mfma16(s16x4 a, s16x4 b, f32x4 c) {
#if __has_builtin(__builtin_amdgcn_mfma_f32_16x16x16bf16_1k)
    return __builtin_amdgcn_mfma_f32_16x16x16bf16_1k(a, b, c, 0, 0, 0);
#else
    f32x4 d;
    asm volatile("v_mfma_f32_16x16x16_bf16 %0, %1, %2, %3"
                 : "=v"(d) : "v"(a), "v"(b), "v"(c));
    return d;
#endif
}

static __device__ __forceinline__ float fast_exp2(float x) {
#if __has_builtin(__builtin_amdgcn_exp2f)
    return __builtin_amdgcn_exp2f(x);
#else
    return exp2f(x);
#endif
}

static __device__ __forceinline__ float fast_rcp(float x) {
#if __has_builtin(__builtin_amdgcn_rcpf)
    return __builtin_amdgcn_rcpf(x);
#else
    return 1.0f / x;
#endif
}

// ---- workspace layout (bytes) ----
#define OFF_WQT_HI 0        // Q,K transposed A-frags: 36 frags * 512 el = 36864 B
#define OFF_WQT_LO 36864
#define OFF_WV_HI  73728    // V B-frags: 18 frags * 512 el = 18432 B
#define OFF_WV_LO  92160
#define OFF_WO_HI  110592   // out-proj B-frags: 18 frags
#define OFF_WO_LO  129024
#define OFF_RPE    147456   // rpe * log2e in C-frag layout [h][nt][kt][lane][4] f32 = 98304 B
// total 245760 B

// ---- LDS overlay arena: 16384 B ----
// phase 0/1: xs_hi [64][128]swz ; phase 2/3: o_hi (overlay)
#define LDS_BYTES 16384

// swizzled element index into a [64][128] bf16 buffer (16B-chunk XOR)
static __device__ __forceinline__ int swz(int row, int col) {
    return row * 128 + ((((col >> 3) ^ (row & 15)) & 15) << 3) + (col & 7);
}

__global__ __launch_bounds__(256)
void prep_kernel(const float* __restrict__ wqkv, const float* __restrict__ wout,
                 const float* __restrict__ rpe, char* __restrict__ ws)
{
    bf16_t* wqt_hi = (bf16_t*)(ws + OFF_WQT_HI);
    bf16_t* wqt_lo = (bf16_t*)(ws + OFF_WQT_LO);
    bf16_t* wv_hi  = (bf16_t*)(ws + OFF_WV_HI);
    bf16_t* wv_lo  = (bf16_t*)(ws + OFF_WV_LO);
    bf16_t* wo_hi  = (bf16_t*)(ws + OFF_WO_HI);
    bf16_t* wo_lo  = (bf16_t*)(ws + OFF_WO_LO);
    float*  rpe_b  = (float*)(ws + OFF_RPE);

    int idx = blockIdx.x * 256 + threadIdx.x;
    {
        int j = idx & 7, lane = (idx >> 3) & 63, frag = idx >> 9;
        int c = lane & 15, g = lane >> 4;
        // Q,K transposed A-frags: lane(c,g) holds W^T[head-dim c][k=ks*32+g*8+j]
        if (idx < 18432) {
            int ks = frag % 3, r2 = frag / 3, wh = r2 % 6, t = r2 / 6;  // t: 0=Q,1=K
            int k = ks * 32 + g * 8 + j;
            float v = wqkv[k * 288 + t * 96 + wh * 16 + c];
            bf16_t h = (bf16_t)v;
            wqt_hi[idx] = h;
            wqt_lo[idx] = (bf16_t)(v - (float)h);
        }
        // V B-frags: lane(c,g) holds Wv[k=ks*32+g*8+j][n=wh*16+c]
        if (idx < 9216) {
            int ks = frag % 3, wh = frag / 3;
            int k = ks * 32 + g * 8 + j;
            float v = wqkv[k * 288 + 192 + wh * 16 + c];
            bf16_t h = (bf16_t)v;
            wv_hi[idx] = h;
            wv_lo[idx] = (bf16_t)(v - (float)h);
            float v2 = wout[k * 96 + wh * 16 + c];
            bf16_t h2 = (bf16_t)v2;
            wo_hi[idx] = h2;
            wo_lo[idx] = (bf16_t)(v2 - (float)h2);
        }
    }
    // rpe * log2e in QK^T C-fragment layout: [h][nt][kt][lane][i]
    if (idx < 24576) {
        int i = idx & 3, lane = (idx >> 2) & 63, kt = (idx >> 8) & 3,
            nt = (idx >> 10) & 3, h = idx >> 12;
        int c = lane & 15, g = lane >> 4;
        int k = kt * 16 + g * 4 + i, q = nt * 16 + c;
        int qr = q >> 3, qc = q & 7, kr = k >> 3, kc = k & 7;
        rpe_b[idx] = rpe[((qr - kr + 7) * 15 + (qc - kc + 7)) * NH + h] * LOG2E;
    }
}

__global__ __launch_bounds__(384, 4)
void swin_mfma(const float* __restrict__ x,
               const float* __restrict__ b_qkv,
               const float* __restrict__ b_out,
               const char*  __restrict__ ws,
               float* __restrict__ out)
{
    extern __shared__ char smem[];
    bf16_t* xs_hi = (bf16_t*)(smem);            // phase 0/1 (swizzled [64][128])
    bf16_t* o_hi  = (bf16_t*)(smem);            // phase 2/3 overlay

    const bf16_t* wqt_hi = (const bf16_t*)(ws + OFF_WQT_HI);
    const bf16_t* wqt_lo = (const bf16_t*)(ws + OFF_WQT_LO);
    const bf16_t* wv_hi  = (const bf16_t*)(ws + OFF_WV_HI);
    const bf16_t* wv_lo  = (const bf16_t*)(ws + OFF_WV_LO);
    const bf16_t* wo_hi  = (const bf16_t*)(ws + OFF_WO_HI);
    const bf16_t* wo_lo  = (const bf16_t*)(ws + OFF_WO_LO);
    const float*  rpe_b  = (const float*)(ws + OFF_RPE);

    const int blk = blockIdx.x;
    const int b   = blk >> 9;          // 512 block-slots per image
    const int wi  = (blk >> 4) & 31;
    const int wj0 = (blk & 15) << 1;   // 2 consecutive windows per block

    const int tid  = threadIdx.x;
    const int lane = tid & 63;
    const int w    = tid >> 6;      // wave = head
    const int g    = lane >> 4;     // lane group 0..3
    const int c    = lane & 15;

    const f32x4 zf = {0.f, 0.f, 0.f, 0.f};
    const int e_wi = (wi == 31);

    #pragma unroll
    for (int ww = 0; ww < 2; ++ww) {
        const int wj = wj0 + ww;
        if (ww) __syncthreads();   // prev window's o-reads done -> xs overlay legal

        // ---- Phase 0: stage x (bf16-hi) -> swizzled xs_hi (shifted gather) ----
        #pragma unroll
        for (int it = 0; it < 4; ++it) {
            int f4  = tid + it * 384;          // float4 index over [64][24]
            int row = f4 / 24, c4 = f4 - row * 24;
            int r = row >> 3, cl = row & 7;
            int gh = (wi * WSZ + r + 4) & 255;
            int gw = (wj * WSZ + cl + 4) & 255;
            const float4 v = *(const float4*)(x + (((size_t)b * HH + gh) * HH + gw) * DD + c4 * 4);
            uint2 hv;
            hv.x = pack2(v.x, v.y); hv.y = pack2(v.z, v.w);
            *(uint2*)&xs_hi[swz(row, c4 * 4)] = hv;
        }
        __syncthreads();

        // ---- Phase 1: QKV projection (2-term split: hi*Whi + hi*Wlo) ----
        f32x4 aq[4], akk[4], av[4];
        {
            const float4 bq4 = *(const float4*)&b_qkv[w * 16 + 4 * g];
            const float4 bk4 = *(const float4*)&b_qkv[96 + w * 16 + 4 * g];
            const float  bv  = b_qkv[192 + w * 16 + c];
            #pragma unroll
            for (int t4 = 0; t4 < 4; ++t4) {
                aq[t4]  = (f32x4){bq4.x, bq4.y, bq4.z, bq4.w};
                akk[t4] = (f32x4){bk4.x, bk4.y, bk4.z, bk4.w};
                av[t4]  = (f32x4){bv, bv, bv, bv};
            }
        }
        #pragma unroll
        for (int ks = 0; ks < 3; ++ks) {
            bf16x8 ah[4];
            #pragma unroll
            for (int mt = 0; mt < 4; ++mt) {
                int e = (mt * 16 + c) * 128 + (((ks * 4 + g) ^ c) << 3);
                ah[mt] = *(const bf16x8*)&xs_hi[e];
            }
            const bf16x8 qh = *(const bf16x8*)&wqt_hi[(w * 3 + ks) * 512 + lane * 8];
            const bf16x8 ql = *(const bf16x8*)&wqt_lo[(w * 3 + ks) * 512 + lane * 8];
            const bf16x8 kh = *(const bf16x8*)&wqt_hi[((6 + w) * 3 + ks) * 512 + lane * 8];
            const bf16x8 kl = *(const bf16x8*)&wqt_lo[((6 + w) * 3 + ks) * 512 + lane * 8];
            const bf16x8 vh = *(const bf16x8*)&wv_hi[(w * 3 + ks) * 512 + lane * 8];
            const bf16x8 vl = *(const bf16x8*)&wv_lo[(w * 3 + ks) * 512 + lane * 8];
            #pragma unroll
            for (int mt = 0; mt < 4; ++mt) {
                aq[mt]  = __builtin_amdgcn_mfma_f32_16x16x32_bf16(qh, ah[mt], aq[mt], 0, 0, 0);
                aq[mt]  = __builtin_amdgcn_mfma_f32_16x16x32_bf16(ql, ah[mt], aq[mt], 0, 0, 0);
                akk[mt] = __builtin_amdgcn_mfma_f32_16x16x32_bf16(kh, ah[mt], akk[mt], 0, 0, 0);
                akk[mt] = __builtin_amdgcn_mfma_f32_16x16x32_bf16(kl, ah[mt], akk[mt], 0, 0, 0);
                av[mt]  = __builtin_amdgcn_mfma_f32_16x16x32_bf16(ah[mt], vh, av[mt], 0, 0, 0);
                av[mt]  = __builtin_amdgcn_mfma_f32_16x16x32_bf16(ah[mt], vl, av[mt], 0, 0, 0);
            }
        }
        __syncthreads();   // all proj reads of xs done -> o overlay becomes legal

        // convert proj outputs to 16x16x16 MFMA fragments (all lane-local)
        s16x4 aqb[4], akb[4], avb[4];
        #pragma unroll
        for (int t = 0; t < 4; ++t) {
            Upk uq, uk, uv;
            const float qs = 0.25f * LOG2E;     // fold 1/sqrt(dk) and log2e
            uq.u[0] = pack2(aq[t][0] * qs, aq[t][1] * qs);
            uq.u[1] = pack2(aq[t][2] * qs, aq[t][3] * qs);
            uk.u[0] = pack2(akk[t][0], akk[t][1]);
            uk.u[1] = pack2(akk[t][2], akk[t][3]);
            uv.u[0] = pack2(av[t][0], av[t][1]);
            uv.u[1] = pack2(av[t][2], av[t][3]);
            aqb[t] = uq.s; akb[t] = uk.s; avb[t] = uv.s;
        }

        // ---- Phase 2: attention, fully in registers ----
        const int e_wj = (wj == 31);
        const bool edge = e_wi || e_wj;
        int rk[4][4];
        #pragma unroll
        for (int kt = 0; kt < 4; ++kt)
            #pragma unroll
            for (int i = 0; i < 4; ++i) {
                int k = kt * 16 + g * 4 + i;
                int kr = k >> 3, kc = k & 7;
                rk[kt][i] = (e_wi ? (kr >= 4 ? 2 : 1) : 0) * 3 + (e_wj ? (kc >= 4 ? 2 : 1) : 0);
            }

        #pragma unroll
        for (int nt = 0; nt < 4; ++nt) {
            // QK^T with rpe pre-loaded as MFMA C-in (C layout matches rpe_b frag layout)
            f32x4 stc[4];
            #pragma unroll
            for (int kt = 0; kt < 4; ++kt) {
                const f32x4 rc = *(const f32x4*)&rpe_b[(((w * 4 + nt) * 4 + kt) << 8) + lane * 4];
                stc[kt] = mfma16(akb[kt], aqb[nt], rc);
            }

            int q = nt * 16 + c, qr = q >> 3, qc = q & 7;
            int rq = (e_wi ? (qr >= 4 ? 2 : 1) : 0) * 3 + (e_wj ? (qc >= 4 ? 2 : 1) : 0);
            // no max-subtraction: scores are bounded (|s| << 88); masked -> exp2(-1e9)=0
            float sv[16];
            float sum = 0.f;
            #pragma unroll
            for (int kt = 0; kt < 4; ++kt)
                #pragma unroll
                for (int i = 0; i < 4; ++i) {
                    float s = stc[kt][i];
                    if (edge && (rk[kt][i] != rq)) s = -1e9f;
                    s = fast_exp2(s);
                    sv[kt * 4 + i] = s;
                    sum += s;
                }
            sum += __shfl_xor(sum, 16);
            sum += __shfl_xor(sum, 32);
            const float rinv = fast_rcp(sum);

            // PV: O^T tile = sum_ks V^T-frag x P^T-frag (unnormalized P; scale output)
            f32x4 oa = zf;
            #pragma unroll
            for (int ks2 = 0; ks2 < 4; ++ks2) {
                Upk pb;
                pb.u[0] = pack2(sv[ks2 * 4 + 0], sv[ks2 * 4 + 1]);
                pb.u[1] = pack2(sv[ks2 * 4 + 2], sv[ks2 * 4 + 3]);
                oa = mfma16(avb[ks2], pb.s, oa);
            }
            // write O (bf16-hi, normalized) into swizzled o buffer
            {
                uint2 hv;
                hv.x = pack2(oa[0] * rinv, oa[1] * rinv);
                hv.y = pack2(oa[2] * rinv, oa[3] * rinv);
                *(uint2*)&o_hi[swz(nt * 16 + c, w * 16 + 4 * g)] = hv;
            }
        }
        __syncthreads();

        // ---- Phase 3: out-projection (2-term split). C[row=mt*16+4g+i][col=w*16+c] ----
        f32x4 acc3[4];
        {
            const float boc = b_out[w * 16 + c];
            #pragma unroll
            for (int mt = 0; mt < 4; ++mt) acc3[mt] = (f32x4){boc, boc, boc, boc};
        }
        #pragma unroll
        for (int ks = 0; ks < 3; ++ks) {
            bf16x8 ah[4];
            #pragma unroll
            for (int mt = 0; mt < 4; ++mt) {
                int e = (mt * 16 + c) * 128 + (((ks * 4 + g) ^ c) << 3);
                ah[mt] = *(const bf16x8*)&o_hi[e];
            }
            const bf16x8 bh = *(const bf16x8*)&wo_hi[(w * 3 + ks) * 512 + lane * 8];
            const bf16x8 bl = *(const bf16x8*)&wo_lo[(w * 3 + ks) * 512 + lane * 8];
            #pragma unroll
            for (int mt = 0; mt < 4; ++mt) {
                acc3[mt] = __builtin_amdgcn_mfma_f32_16x16x32_bf16(ah[mt], bh, acc3[mt], 0, 0, 0);
                acc3[mt] = __builtin_amdgcn_mfma_f32_16x16x32_bf16(ah[mt], bl, acc3[mt], 0, 0, 0);
            }
        }
        // store (shifted scatter): lane(c,g) holds out[row=mt*16+g*4+i][col=w*16+c]
        #pragma unroll
        for (int mt = 0; mt < 4; ++mt)
            #pragma unroll
            for (int i = 0; i < 4; ++i) {
                int row = mt * 16 + g * 4 + i;
                int r = row >> 3, cl = row & 7;
                int gh = (wi * WSZ + r + 4) & 255;
                int gw = (wj * WSZ + cl + 4) & 255;
                out[(((size_t)b * HH + gh) * HH + gw) * DD + w * 16 + c] = acc3[mt][i];
            }
    }
}

extern "C" void kernel_launch(void* const* d_in, const int* in_sizes, int n_in,
                              void* d_out, int out_size, void* d_ws, size_t ws_size,
                              hipStream_t stream) {
    const float* x    = (const float*)d_in[0];
    const float* wqkv = (const float*)d_in[1];
    const float* bqkv = (const float*)d_in[2];
    const float* wout = (const float*)d_in[3];
    const float* bout = (const float*)d_in[4];
    const float* rpe  = (const float*)d_in[5];
    float* out = (float*)d_out;
    char* ws = (char*)d_ws;

    const int B = in_sizes[0] / (HH * HH * DD);

    hipLaunchKernelGGL(prep_kernel, dim3(96), dim3(256), 0, stream, wqkv, wout, rpe, ws);
    hipLaunchKernelGGL(swin_mfma, dim3(B * 512), dim3(384), LDS_BYTES, stream,
                       x, bqkv, bout, (const char*)ws, out);
}

// Round 11
// 186.621 us; speedup vs baseline: 4.1119x; 1.1531x over previous
//
#include <hip/hip_runtime.h>
#include <stdint.h>

#define HH    256
#define DD    96
#define NH    6
#define WSZ   8

typedef __bf16 bf16_t;
typedef bf16_t bf16x8 __attribute__((ext_vector_type(8)));
typedef short  s16x4  __attribute__((ext_vector_type(4)));
typedef float  f32x4  __attribute__((ext_vector_type(4)));

union U2  { bf16_t h[2]; uint32_t u; };
union Upk { uint32_t u[2]; s16x4 s; };

#define LOG2E 1.44269504088896f

static __device__ __forceinline__ uint32_t pack2(float a, float b) {
    U2 x; x.h[0] = (bf16_t)a; x.h[1] = (bf16_t)b; return x.u;
}

static __device__ __forceinline__ f32x4 mfma16(s16x4 a, s16x4 b, f32x4 c) {
#if __has_builtin(__builtin_amdgcn_mfma_f32_16x16x16bf16_1k)
    return __builtin_amdgcn_mfma_f32_16x16x16bf16_1k(a, b, c, 0, 0, 0);
#else
    f32x4 d;
    asm volatile("v_mfma_f32_16x16x16_bf16 %0, %1, %2, %3"
                 : "=v"(d) : "v"(a), "v"(b), "v"(c));
    return d;
#endif
}

static __device__ __forceinline__ float fast_exp2(float x) {
#if __has_builtin(__builtin_amdgcn_exp2f)
    return __builtin_amdgcn_exp2f(x);
#else
    return exp2f(x);
#endif
}

static __device__ __forceinline__ float fast_rcp(float x) {
#if __has_builtin(__builtin_amdgcn_rcpf)
    return __builtin_amdgcn_rcpf(x);
#else
    return 1.0f / x;
#endif
}

// ---- workspace layout (bytes) ----
#define OFF_WQT_HI 0        // Q,K transposed A-frags: 36 frags * 512 el = 36864 B
#define OFF_WQT_LO 36864
#define OFF_WV_HI  73728    // V B-frags: 18 frags * 512 el = 18432 B
#define OFF_WV_LO  92160
#define OFF_WO_HI  110592   // out-proj B-frags: 18 frags
#define OFF_WO_LO  129024
#define OFF_RPE    147456   // rpe * log2e in C-frag layout [h][nt][kt][lane][4] f32 = 98304 B
// total 245760 B

// swizzled element index into a [64][128] bf16 buffer (16B-chunk XOR)
static __device__ __forceinline__ int swz(int row, int col) {
    return row * 128 + ((((col >> 3) ^ (row & 15)) & 15) << 3) + (col & 7);
}

__global__ __launch_bounds__(256)
void prep_kernel(const float* __restrict__ wqkv, const float* __restrict__ wout,
                 const float* __restrict__ rpe, char* __restrict__ ws)
{
    bf16_t* wqt_hi = (bf16_t*)(ws + OFF_WQT_HI);
    bf16_t* wqt_lo = (bf16_t*)(ws + OFF_WQT_LO);
    bf16_t* wv_hi  = (bf16_t*)(ws + OFF_WV_HI);
    bf16_t* wv_lo  = (bf16_t*)(ws + OFF_WV_LO);
    bf16_t* wo_hi  = (bf16_t*)(ws + OFF_WO_HI);
    bf16_t* wo_lo  = (bf16_t*)(ws + OFF_WO_LO);
    float*  rpe_b  = (float*)(ws + OFF_RPE);

    int idx = blockIdx.x * 256 + threadIdx.x;
    {
        int j = idx & 7, lane = (idx >> 3) & 63, frag = idx >> 9;
        int c = lane & 15, g = lane >> 4;
        // Q,K transposed A-frags: lane(c,g) holds W^T[head-dim c][k=ks*32+g*8+j]
        if (idx < 18432) {
            int ks = frag % 3, r2 = frag / 3, wh = r2 % 6, t = r2 / 6;  // t: 0=Q,1=K
            int k = ks * 32 + g * 8 + j;
            float v = wqkv[k * 288 + t * 96 + wh * 16 + c];
            bf16_t h = (bf16_t)v;
            wqt_hi[idx] = h;
            wqt_lo[idx] = (bf16_t)(v - (float)h);
        }
        // V B-frags: lane(c,g) holds Wv[k=ks*32+g*8+j][n=wh*16+c]
        if (idx < 9216) {
            int ks = frag % 3, wh = frag / 3;
            int k = ks * 32 + g * 8 + j;
            float v = wqkv[k * 288 + 192 + wh * 16 + c];
            bf16_t h = (bf16_t)v;
            wv_hi[idx] = h;
            wv_lo[idx] = (bf16_t)(v - (float)h);
            float v2 = wout[k * 96 + wh * 16 + c];
            bf16_t h2 = (bf16_t)v2;
            wo_hi[idx] = h2;
            wo_lo[idx] = (bf16_t)(v2 - (float)h2);
        }
    }
    // rpe * log2e in QK^T C-fragment layout: [h][nt][kt][lane][i]
    if (idx < 24576) {
        int i = idx & 3, lane = (idx >> 2) & 63, kt = (idx >> 8) & 3,
            nt = (idx >> 10) & 3, h = idx >> 12;
        int c = lane & 15, g = lane >> 4;
        int k = kt * 16 + g * 4 + i, q = nt * 16 + c;
        int qr = q >> 3, qc = q & 7, kr = k >> 3, kc = k & 7;
        rpe_b[idx] = rpe[((qr - kr + 7) * 15 + (qc - kc + 7)) * NH + h] * LOG2E;
    }
}

// 768 threads = 12 waves: waves 0-5 -> window wj0 (heads 0-5), waves 6-11 -> window wj0+1.
// Each window-half owns a 16 KB LDS arena (xs overlay o). Static LDS: 32 KB total.
__global__ __launch_bounds__(768, 4)
void swin_mfma(const float* __restrict__ x,
               const float* __restrict__ b_qkv,
               const float* __restrict__ b_out,
               const char*  __restrict__ ws,
               float* __restrict__ out)
{
    __shared__ char smem[32768];

    const int tid  = threadIdx.x;
    const int w2   = tid >> 6;          // wave 0..11
    const int wv   = (w2 >= 6) ? 1 : 0; // window half
    const int w    = w2 - 6 * wv;       // head 0..5
    const int lane = tid & 63;
    const int g    = lane >> 4;
    const int c    = lane & 15;
    const int tl   = tid - (wv << 8) - (wv << 7);   // tid - wv*384: 0..383 within half

    bf16_t* xs_hi = (bf16_t*)(smem + (wv << 14));   // phase 0/1 arena (swizzled [64][128])
    bf16_t* o_hi  = xs_hi;                          // phase 2/3 overlay

    const bf16_t* wqt_hi = (const bf16_t*)(ws + OFF_WQT_HI);
    const bf16_t* wqt_lo = (const bf16_t*)(ws + OFF_WQT_LO);
    const bf16_t* wv_hi  = (const bf16_t*)(ws + OFF_WV_HI);
    const bf16_t* wv_lo  = (const bf16_t*)(ws + OFF_WV_LO);
    const bf16_t* wo_hi  = (const bf16_t*)(ws + OFF_WO_HI);
    const bf16_t* wo_lo  = (const bf16_t*)(ws + OFF_WO_LO);
    const float*  rpe_b  = (const float*)(ws + OFF_RPE);

    const int blk = blockIdx.x;
    const int b   = blk >> 9;                 // 512 blocks per image
    const int wi  = (blk >> 4) & 31;
    const int wj  = ((blk & 15) << 1) + wv;   // this half's window column

    const f32x4 zf = {0.f, 0.f, 0.f, 0.f};

    // ---- Phase 0: stage x (bf16-hi) -> swizzled xs_hi (shifted gather) ----
    #pragma unroll
    for (int it = 0; it < 4; ++it) {
        int f4  = tl + it * 384;          // float4 index over [64][24]
        int row = f4 / 24, c4 = f4 - row * 24;
        int r = row >> 3, cl = row & 7;
        int gh = (wi * WSZ + r + 4) & 255;
        int gw = (wj * WSZ + cl + 4) & 255;
        const float4 v = *(const float4*)(x + (((size_t)b * HH + gh) * HH + gw) * DD + c4 * 4);
        uint2 hv;
        hv.x = pack2(v.x, v.y); hv.y = pack2(v.z, v.w);
        *(uint2*)&xs_hi[swz(row, c4 * 4)] = hv;
    }
    __syncthreads();

    // ---- Phase 1: QKV projection (2-term split: hi*Whi + hi*Wlo) ----
    f32x4 aq[4], akk[4], av[4];
    {
        const float4 bq4 = *(const float4*)&b_qkv[w * 16 + 4 * g];
        const float4 bk4 = *(const float4*)&b_qkv[96 + w * 16 + 4 * g];
        const float  bv  = b_qkv[192 + w * 16 + c];
        #pragma unroll
        for (int t4 = 0; t4 < 4; ++t4) {
            aq[t4]  = (f32x4){bq4.x, bq4.y, bq4.z, bq4.w};
            akk[t4] = (f32x4){bk4.x, bk4.y, bk4.z, bk4.w};
            av[t4]  = (f32x4){bv, bv, bv, bv};
        }
    }
    #pragma unroll
    for (int ks = 0; ks < 3; ++ks) {
        bf16x8 ah[4];
        #pragma unroll
        for (int mt = 0; mt < 4; ++mt) {
            int e = (mt * 16 + c) * 128 + (((ks * 4 + g) ^ c) << 3);
            ah[mt] = *(const bf16x8*)&xs_hi[e];
        }
        const bf16x8 qh = *(const bf16x8*)&wqt_hi[(w * 3 + ks) * 512 + lane * 8];
        const bf16x8 ql = *(const bf16x8*)&wqt_lo[(w * 3 + ks) * 512 + lane * 8];
        const bf16x8 kh = *(const bf16x8*)&wqt_hi[((6 + w) * 3 + ks) * 512 + lane * 8];
        const bf16x8 kl = *(const bf16x8*)&wqt_lo[((6 + w) * 3 + ks) * 512 + lane * 8];
        const bf16x8 vh = *(const bf16x8*)&wv_hi[(w * 3 + ks) * 512 + lane * 8];
        const bf16x8 vl = *(const bf16x8*)&wv_lo[(w * 3 + ks) * 512 + lane * 8];
        #pragma unroll
        for (int mt = 0; mt < 4; ++mt) {
            aq[mt]  = __builtin_amdgcn_mfma_f32_16x16x32_bf16(qh, ah[mt], aq[mt], 0, 0, 0);
            aq[mt]  = __builtin_amdgcn_mfma_f32_16x16x32_bf16(ql, ah[mt], aq[mt], 0, 0, 0);
            akk[mt] = __builtin_amdgcn_mfma_f32_16x16x32_bf16(kh, ah[mt], akk[mt], 0, 0, 0);
            akk[mt] = __builtin_amdgcn_mfma_f32_16x16x32_bf16(kl, ah[mt], akk[mt], 0, 0, 0);
            av[mt]  = __builtin_amdgcn_mfma_f32_16x16x32_bf16(ah[mt], vh, av[mt], 0, 0, 0);
            av[mt]  = __builtin_amdgcn_mfma_f32_16x16x32_bf16(ah[mt], vl, av[mt], 0, 0, 0);
        }
    }
    __syncthreads();   // all proj reads of xs done -> o overlay becomes legal

    // convert proj outputs to 16x16x16 MFMA fragments (all lane-local)
    s16x4 aqb[4], akb[4], avb[4];
    #pragma unroll
    for (int t = 0; t < 4; ++t) {
        Upk uq, uk, uv;
        const float qs = 0.25f * LOG2E;     // fold 1/sqrt(dk) and log2e
        uq.u[0] = pack2(aq[t][0] * qs, aq[t][1] * qs);
        uq.u[1] = pack2(aq[t][2] * qs, aq[t][3] * qs);
        uk.u[0] = pack2(akk[t][0], akk[t][1]);
        uk.u[1] = pack2(akk[t][2], akk[t][3]);
        uv.u[0] = pack2(av[t][0], av[t][1]);
        uv.u[1] = pack2(av[t][2], av[t][3]);
        aqb[t] = uq.s; akb[t] = uk.s; avb[t] = uv.s;
    }

    // ---- Phase 2: attention, fully in registers ----
    const int e_wi = (wi == 31), e_wj = (wj == 31);
    const bool edge = e_wi || e_wj;
    int rk[4][4];
    #pragma unroll
    for (int kt = 0; kt < 4; ++kt)
        #pragma unroll
        for (int i = 0; i < 4; ++i) {
            int k = kt * 16 + g * 4 + i;
            int kr = k >> 3, kc = k & 7;
            rk[kt][i] = (e_wi ? (kr >= 4 ? 2 : 1) : 0) * 3 + (e_wj ? (kc >= 4 ? 2 : 1) : 0);
        }

    #pragma unroll
    for (int nt = 0; nt < 4; ++nt) {
        // QK^T with rpe pre-loaded as MFMA C-in (C layout matches rpe_b frag layout)
        f32x4 stc[4];
        #pragma unroll
        for (int kt = 0; kt < 4; ++kt) {
            const f32x4 rc = *(const f32x4*)&rpe_b[(((w * 4 + nt) * 4 + kt) << 8) + lane * 4];
            stc[kt] = mfma16(akb[kt], aqb[nt], rc);
        }

        int q = nt * 16 + c, qr = q >> 3, qc = q & 7;
        int rq = (e_wi ? (qr >= 4 ? 2 : 1) : 0) * 3 + (e_wj ? (qc >= 4 ? 2 : 1) : 0);
        // no max-subtraction: scores bounded (|s| << 88); masked -> exp2(-1e9)=0
        float sv[16];
        float sum = 0.f;
        #pragma unroll
        for (int kt = 0; kt < 4; ++kt)
            #pragma unroll
            for (int i = 0; i < 4; ++i) {
                float s = stc[kt][i];
                if (edge && (rk[kt][i] != rq)) s = -1e9f;
                s = fast_exp2(s);
                sv[kt * 4 + i] = s;
                sum += s;
            }
        sum += __shfl_xor(sum, 16);
        sum += __shfl_xor(sum, 32);
        const float rinv = fast_rcp(sum);

        // PV: O^T tile = sum_ks V^T-frag x P^T-frag (unnormalized P; scale output)
        f32x4 oa = zf;
        #pragma unroll
        for (int ks2 = 0; ks2 < 4; ++ks2) {
            Upk pb;
            pb.u[0] = pack2(sv[ks2 * 4 + 0], sv[ks2 * 4 + 1]);
            pb.u[1] = pack2(sv[ks2 * 4 + 2], sv[ks2 * 4 + 3]);
            oa = mfma16(avb[ks2], pb.s, oa);
        }
        // write O (bf16-hi, normalized) into swizzled o buffer
        {
            uint2 hv;
            hv.x = pack2(oa[0] * rinv, oa[1] * rinv);
            hv.y = pack2(oa[2] * rinv, oa[3] * rinv);
            *(uint2*)&o_hi[swz(nt * 16 + c, w * 16 + 4 * g)] = hv;
        }
    }
    __syncthreads();

    // ---- Phase 3: out-projection (2-term split). C[row=mt*16+4g+i][col=w*16+c] ----
    f32x4 acc3[4];
    {
        const float boc = b_out[w * 16 + c];
        #pragma unroll
        for (int mt = 0; mt < 4; ++mt) acc3[mt] = (f32x4){boc, boc, boc, boc};
    }
    #pragma unroll
    for (int ks = 0; ks < 3; ++ks) {
        bf16x8 ah[4];
        #pragma unroll
        for (int mt = 0; mt < 4; ++mt) {
            int e = (mt * 16 + c) * 128 + (((ks * 4 + g) ^ c) << 3);
            ah[mt] = *(const bf16x8*)&o_hi[e];
        }
        const bf16x8 bh = *(const bf16x8*)&wo_hi[(w * 3 + ks) * 512 + lane * 8];
        const bf16x8 bl = *(const bf16x8*)&wo_lo[(w * 3 + ks) * 512 + lane * 8];
        #pragma unroll
        for (int mt = 0; mt < 4; ++mt) {
            acc3[mt] = __builtin_amdgcn_mfma_f32_16x16x32_bf16(ah[mt], bh, acc3[mt], 0, 0, 0);
            acc3[mt] = __builtin_amdgcn_mfma_f32_16x16x32_bf16(ah[mt], bl, acc3[mt], 0, 0, 0);
        }
    }
    // store (shifted scatter): lane(c,g) holds out[row=mt*16+g*4+i][col=w*16+c]
    #pragma unroll
    for (int mt = 0; mt < 4; ++mt)
        #pragma unroll
        for (int i = 0; i < 4; ++i) {
            int row = mt * 16 + g * 4 + i;
            int r = row >> 3, cl = row & 7;
            int gh = (wi * WSZ + r + 4) & 255;
            int gw = (wj * WSZ + cl + 4) & 255;
            out[(((size_t)b * HH + gh) * HH + gw) * DD + w * 16 + c] = acc3[mt][i];
        }
}

extern "C" void kernel_launch(void* const* d_in, const int* in_sizes, int n_in,
                              void* d_out, int out_size, void* d_ws, size_t ws_size,
                              hipStream_t stream) {
    const float* x    = (const float*)d_in[0];
    const float* wqkv = (const float*)d_in[1];
    const float* bqkv = (const float*)d_in[2];
    const float* wout = (const float*)d_in[3];
    const float* bout = (const float*)d_in[4];
    const float* rpe  = (const float*)d_in[5];
    float* out = (float*)d_out;
    char* ws = (char*)d_ws;

    const int B = in_sizes[0] / (HH * HH * DD);

    hipLaunchKernelGGL(prep_kernel, dim3(96), dim3(256), 0, stream, wqkv, wout, rpe, ws);
    hipLaunchKernelGGL(swin_mfma, dim3(B * 512), dim3(768), 0, stream,
                       x, bqkv, bout, (const char*)ws, out);
}